// Round 6
// baseline (95.824 us; speedup 1.0000x reference)
//
#include <hip/hip_runtime.h>

// HEGN loss: L_reg + bidirectional chamfer(x, y).  B=8, N=M=4096.
// Single-pass chamfer: each block owns 64 queries and loops over ALL 4096
// refs (16 double-buffered LDS chunks).  Ref-loop is split across G=32
// threads (half-wave); final min via 5x shfl_xor.  No partial workspace,
// no second kernel.  (Cooperative fuse measured +52us in R3 -- not used.)
#define BB 8
#define NN 4096
#define MC 256                     // refs staged per chunk
#define NCHUNK (NN / MC)           // 16
#define KPT 8                      // queries per group
#define G 32                       // threads per query-group (half-wave)
#define TPB 256
#define QPB (KPT * TPB / G)        // 64 queries per block
#define GRID_X (NN / QPB)          // 64; grid = (64, 16) = 1024 blocks

typedef float f32x4 __attribute__((ext_vector_type(4)));

// 4 refs x KPT queries: 12 fma + 2 min3 per query (112 VALU at KPT=8).
#define CHAMFER_BODY(w0, w1, w2, w3)                                           \
  _Pragma("unroll") for (int k = 0; k < KPT; k++) {                            \
    const float s0 =                                                           \
        fmaf(px[k], w0.x, fmaf(py[k], w0.y, fmaf(pz[k], w0.z, w0.w)));         \
    const float s1 =                                                           \
        fmaf(px[k], w1.x, fmaf(py[k], w1.y, fmaf(pz[k], w1.z, w1.w)));         \
    const float s2 =                                                           \
        fmaf(px[k], w2.x, fmaf(py[k], w2.y, fmaf(pz[k], w2.z, w2.w)));         \
    const float s3 =                                                           \
        fmaf(px[k], w3.x, fmaf(py[k], w3.y, fmaf(pz[k], w3.z, w3.w)));         \
    m[k] = fminf(fminf(s0, s1), m[k]); /* -> v_min3_f32 */                     \
    m[k] = fminf(fminf(s2, s3), m[k]); /* -> v_min3_f32 */                     \
  }

__global__ __launch_bounds__(TPB) void hegn_loss(
    const float* __restrict__ X, const float* __restrict__ Y,
    const float* __restrict__ R, const float* __restrict__ S,
    const float* __restrict__ t, const float* __restrict__ Rgt,
    const float* __restrict__ Sgt, const float* __restrict__ tgt,
    float* __restrict__ out) {
  __shared__ float4 ly[2][MC];     // (-2*r0, -2*r1, -2*r2, |r|^2); 8 KB
  const int tid = threadIdx.x;
  const int zb  = blockIdx.y;      // (dir<<3) | b
  const int b   = zb & (BB - 1);
  const int dir = zb >> 3;
  const float* pts  = dir ? (Y + b * NN * 3) : (X + b * NN * 3);
  const float* refs = dir ? (X + b * NN * 3) : (Y + b * NN * 3);
  const int g  = tid >> 5;         // query group 0..7
  const int t4 = tid & (G - 1);    // lane within group (ref slice)

  // Load this group's KPT queries (all 32 lanes redundantly; L1-served).
  float px[KPT], py[KPT], pz[KPT], pn[KPT], m[KPT];
  const int q0 = blockIdx.x * QPB + g * KPT;
#pragma unroll
  for (int k = 0; k < KPT; k++) {
    const int p = q0 + k;
    px[k] = pts[p * 3 + 0];
    py[k] = pts[p * 3 + 1];
    pz[k] = pts[p * 3 + 2];
    pn[k] = px[k] * px[k] + py[k] * py[k] + pz[k] * pz[k];
    m[k] = 1e30f;
  }

  // Stage chunk 0.
  {
    const float a0 = refs[tid * 3 + 0];
    const float a1 = refs[tid * 3 + 1];
    const float a2 = refs[tid * 3 + 2];
    ly[0][tid] = make_float4(-2.0f * a0, -2.0f * a1, -2.0f * a2,
                             a0 * a0 + a1 * a1 + a2 * a2);
  }

  // Chunk loop, double-buffered: issue chunk c+1 global loads, barrier,
  // compute chunk c (hides the ~500cy global latency), barrier, ds_write.
#pragma unroll 1
  for (int c = 0; c < NCHUNK; c++) {
    const int cur = c & 1;
    float a0 = 0.f, a1 = 0.f, a2 = 0.f;
    if (c + 1 < NCHUNK) {
      const int j = (c + 1) * MC + tid;
      a0 = refs[j * 3 + 0];
      a1 = refs[j * 3 + 1];
      a2 = refs[j * 3 + 2];
    }
    __syncthreads();               // chunk-c writes visible; prev compute done

    // Thread's slice of the chunk: refs {t4 + 32*s}, s = 0..7 (2 bodies).
    // Reads: lanes 0..31 consecutive 16B -> conflict-free; lanes 32..63
    // duplicate them -> 2-way broadcast (free).
#pragma unroll
    for (int bb = 0; bb < 2; bb++) {
      const float4 w0 = ly[cur][bb * 128 + 0 * G + t4];
      const float4 w1 = ly[cur][bb * 128 + 1 * G + t4];
      const float4 w2 = ly[cur][bb * 128 + 2 * G + t4];
      const float4 w3 = ly[cur][bb * 128 + 3 * G + t4];
      CHAMFER_BODY(w0, w1, w2, w3)
    }
    __syncthreads();               // all compute on ly[1-cur]'s old data done
    if (c + 1 < NCHUNK)
      ly[1 - cur][tid] = make_float4(-2.0f * a0, -2.0f * a1, -2.0f * a2,
                                     a0 * a0 + a1 * a1 + a2 * a2);
  }

  // Min across the 32 lanes of each half-wave group (xor masks stay in-half).
#pragma unroll
  for (int k = 0; k < KPT; k++) {
    float v = m[k];
    v = fminf(v, __shfl_xor(v, 1));
    v = fminf(v, __shfl_xor(v, 2));
    v = fminf(v, __shfl_xor(v, 4));
    v = fminf(v, __shfl_xor(v, 8));
    v = fminf(v, __shfl_xor(v, 16));
    m[k] = v;
  }

  __shared__ float gsum[TPB / G];  // 8 group sums
  if (t4 == 0) {
    float qs = 0.0f;
#pragma unroll
    for (int k = 0; k < KPT; k++) qs += m[k] + pn[k];
    gsum[g] = qs;
  }
  __syncthreads();
  if (tid == 0) {
    float bs = 0.0f;
#pragma unroll
    for (int i = 0; i < TPB / G; i++) bs += gsum[i];
    atomicAdd(out, bs * (1.0f / (float)(BB * NN)));
  }

  // L_reg: one designated block.
  if (blockIdx.x == 0 && blockIdx.y == 0) {
    float v = 0.0f;
    if (tid < 72) {                       // R @ R_gt^T - I, squared
      const int bb = tid / 9, ik = tid % 9, i = ik / 3, k = ik % 3;
      const float* Rb = R + bb * 9;
      const float* Gb = Rgt + bb * 9;
      float d = Rb[i * 3 + 0] * Gb[k * 3 + 0] +
                Rb[i * 3 + 1] * Gb[k * 3 + 1] +
                Rb[i * 3 + 2] * Gb[k * 3 + 2];
      d -= (i == k) ? 1.0f : 0.0f;
      v = d * d;
    } else if (tid < 96) {                // (S - S_gt)^2
      const int i = tid - 72;
      const float d = S[i] - Sgt[i];
      v = d * d;
    } else if (tid < 120) {               // (t - t_gt)^2
      const int i = tid - 96;
      const float d = t[i] - tgt[i];
      v = d * d;
    }
    for (int o = 32; o > 0; o >>= 1) v += __shfl_down(v, o);
    __shared__ float rsum[4];
    if ((tid & 63) == 0) rsum[tid >> 6] = v;
    __syncthreads();
    if (tid == 0) atomicAdd(out, rsum[0] + rsum[1] + rsum[2] + rsum[3]);
  }
}

extern "C" void kernel_launch(void* const* d_in, const int* in_sizes, int n_in,
                              void* d_out, int out_size, void* d_ws, size_t ws_size,
                              hipStream_t stream) {
  const float* X   = (const float*)d_in[0];
  const float* Y   = (const float*)d_in[1];
  const float* R   = (const float*)d_in[2];
  const float* S   = (const float*)d_in[3];
  const float* t   = (const float*)d_in[4];
  const float* Rgt = (const float*)d_in[5];
  const float* Sgt = (const float*)d_in[6];
  const float* tgt = (const float*)d_in[7];

  float* out = (float*)d_out;
  hipMemsetAsync(out, 0, sizeof(float), stream);

  dim3 gA(GRID_X, 2 * BB);        // (64, 16) = 1024 blocks, 4 per CU
  hegn_loss<<<gA, TPB, 0, stream>>>(X, Y, R, S, t, Rgt, Sgt, tgt, out);
}

// Round 7
// 90.173 us; speedup vs baseline: 1.0627x; 1.0627x over previous
//
#include <hip/hip_runtime.h>

// HEGN loss: L_reg + bidirectional chamfer(x, y).  B=8, N=M=4096.
// Best-measured structure (R1, 91.46us): two plain launches, KPT=4, MC=256,
// 1024 blocks.  Seven structural variants (fused-coop, single-pass, asm
// pipeline, pk_fma, KPT/MC sweeps) all landed within 91.5-96.6us -> e2e is
// dominated by the harness's ~40us poison fill + reset dispatch train; the
// chamfer loop is at its ~12-14us VALU-issue floor.
#define BB 8
#define NN 4096
#define MC 256                    // reference points staged per chunk
#define NCHUNK (NN / MC)          // 16
#define KPT 4                     // query points per thread -> 1024 blocks
#define TPB 256
#define PTS_PER_BLOCK (TPB * KPT) // 1024
#define NPTS (2 * BB * NN)        // 65536 (both directions)

// ws layout: partial[c][zb][p]  c in [0,16), zb in [0,16), p in [0,4096) -> 4 MB

__global__ __launch_bounds__(TPB) void chamfer_partial(
    const float* __restrict__ X, const float* __restrict__ Y,
    float* __restrict__ partial, float* __restrict__ out) {
  __shared__ float4 ly[MC];       // (-2*y0, -2*y1, -2*y2, |y|^2)
  const int tid = threadIdx.x;
  const int zb  = blockIdx.z;     // (dir<<3) | b
  const int b   = zb & (BB - 1);
  const int dir = zb >> 3;
  const float* pts  = dir ? (Y + b * NN * 3) : (X + b * NN * 3);
  const float* refs = dir ? (X + b * NN * 3) : (Y + b * NN * 3);
  const int c = blockIdx.y;

  // Replaces the 4-byte hipMemsetAsync dispatch (worth -3.1us, R0->R1).
  // Safe: chamfer_reduce only touches out after this kernel completes.
  if (tid == 0 && blockIdx.x == 0 && blockIdx.y == 0 && blockIdx.z == 0)
    *out = 0.0f;

  {
    const int j = c * MC + tid;   // MC == TPB: one staging iteration
    const float a0 = refs[j * 3 + 0];
    const float a1 = refs[j * 3 + 1];
    const float a2 = refs[j * 3 + 2];
    ly[tid] = make_float4(-2.0f * a0, -2.0f * a1, -2.0f * a2,
                          a0 * a0 + a1 * a1 + a2 * a2);
  }
  __syncthreads();

  float px[KPT], py[KPT], pz[KPT], m[KPT];
  const int p0 = blockIdx.x * PTS_PER_BLOCK + tid;
#pragma unroll
  for (int k = 0; k < KPT; k++) {
    const int p = p0 + k * TPB;
    px[k] = pts[p * 3 + 0];
    py[k] = pts[p * 3 + 1];
    pz[k] = pts[p * 3 + 2];
    m[k] = 1e30f;
  }

  // min over chunk of (|y|^2 - 2 x.y); |x|^2 added after the loop.
#define CHAMFER_BODY(w0, w1, w2, w3)                                           \
  _Pragma("unroll") for (int k = 0; k < KPT; k++) {                            \
    const float s0 =                                                           \
        fmaf(px[k], w0.x, fmaf(py[k], w0.y, fmaf(pz[k], w0.z, w0.w)));         \
    const float s1 =                                                           \
        fmaf(px[k], w1.x, fmaf(py[k], w1.y, fmaf(pz[k], w1.z, w1.w)));         \
    const float s2 =                                                           \
        fmaf(px[k], w2.x, fmaf(py[k], w2.y, fmaf(pz[k], w2.z, w2.w)));         \
    const float s3 =                                                           \
        fmaf(px[k], w3.x, fmaf(py[k], w3.y, fmaf(pz[k], w3.z, w3.w)));         \
    m[k] = fminf(m[k], fminf(fminf(s0, s1), fminf(s2, s3)));                   \
  }

  float4 w0 = ly[0], w1 = ly[1], w2 = ly[2], w3 = ly[3];
#pragma unroll 2
  for (int j = 0; j < MC - 4; j += 4) {
    const float4 n0 = ly[j + 4];
    const float4 n1 = ly[j + 5];
    const float4 n2 = ly[j + 6];
    const float4 n3 = ly[j + 7];
    CHAMFER_BODY(w0, w1, w2, w3)
    w0 = n0; w1 = n1; w2 = n2; w3 = n3;
  }
  CHAMFER_BODY(w0, w1, w2, w3)
#undef CHAMFER_BODY

#pragma unroll
  for (int k = 0; k < KPT; k++) {
    const int p = p0 + k * TPB;
    const float pn = px[k] * px[k] + py[k] * py[k] + pz[k] * pz[k];
    partial[(c * (2 * BB) + zb) * NN + p] = m[k] + pn;
  }
}

// Min across chunks (float4 lanes: 16 coalesced dwordx4 loads per thread,
// all independent), block-sum, 1 atomic per block into out (zeroed by
// chamfer_partial).  Block 0 also adds L_reg.  64 blocks x 256 threads
// cover NPTS/4 float4 slots.
__global__ __launch_bounds__(256) void chamfer_reduce(
    const float4* __restrict__ partial4,
    const float* __restrict__ R, const float* __restrict__ S,
    const float* __restrict__ t, const float* __restrict__ Rgt,
    const float* __restrict__ Sgt, const float* __restrict__ tgt,
    float* __restrict__ out) {
  const int tid = threadIdx.x;
  const int q4 = blockIdx.x * 256 + tid;  // 64 blocks cover NPTS/4 = 16384
  float4 mn = make_float4(1e30f, 1e30f, 1e30f, 1e30f);
#pragma unroll
  for (int c = 0; c < NCHUNK; c++) {
    const float4 v = partial4[c * (NPTS / 4) + q4];
    mn.x = fminf(mn.x, v.x);
    mn.y = fminf(mn.y, v.y);
    mn.z = fminf(mn.z, v.z);
    mn.w = fminf(mn.w, v.w);
  }
  float s = (mn.x + mn.y) + (mn.z + mn.w);
  for (int o = 32; o > 0; o >>= 1) s += __shfl_down(s, o);
  __shared__ float wsum[4];
  if ((tid & 63) == 0) wsum[tid >> 6] = s;
  __syncthreads();
  if (tid == 0) {
    const float bs = wsum[0] + wsum[1] + wsum[2] + wsum[3];
    atomicAdd(out, bs * (1.0f / (float)(BB * NN)));
  }

  if (blockIdx.x == 0) {
    float v = 0.0f;
    if (tid < 72) {                       // R @ R_gt^T - I, squared
      const int b = tid / 9, ik = tid % 9, i = ik / 3, k = ik % 3;
      const float* Rb = R + b * 9;
      const float* Gb = Rgt + b * 9;
      float d = Rb[i * 3 + 0] * Gb[k * 3 + 0] +
                Rb[i * 3 + 1] * Gb[k * 3 + 1] +
                Rb[i * 3 + 2] * Gb[k * 3 + 2];
      d -= (i == k) ? 1.0f : 0.0f;
      v = d * d;
    } else if (tid < 96) {                // (S - S_gt)^2
      const int i = tid - 72;
      const float d = S[i] - Sgt[i];
      v = d * d;
    } else if (tid < 120) {               // (t - t_gt)^2
      const int i = tid - 96;
      const float d = t[i] - tgt[i];
      v = d * d;
    }
    for (int o = 32; o > 0; o >>= 1) v += __shfl_down(v, o);
    __shared__ float rsum[4];
    if ((tid & 63) == 0) rsum[tid >> 6] = v;
    __syncthreads();
    if (tid == 0) atomicAdd(out, rsum[0] + rsum[1] + rsum[2] + rsum[3]);
  }
}

extern "C" void kernel_launch(void* const* d_in, const int* in_sizes, int n_in,
                              void* d_out, int out_size, void* d_ws, size_t ws_size,
                              hipStream_t stream) {
  const float* X   = (const float*)d_in[0];
  const float* Y   = (const float*)d_in[1];
  const float* R   = (const float*)d_in[2];
  const float* S   = (const float*)d_in[3];
  const float* t   = (const float*)d_in[4];
  const float* Rgt = (const float*)d_in[5];
  const float* Sgt = (const float*)d_in[6];
  const float* tgt = (const float*)d_in[7];

  float* partial = (float*)d_ws;
  float* out     = (float*)d_out;

  dim3 gA(NN / PTS_PER_BLOCK, NCHUNK, 2 * BB);   // (4, 16, 16) = 1024 blocks
  chamfer_partial<<<gA, TPB, 0, stream>>>(X, Y, partial, out);

  chamfer_reduce<<<NPTS / 4 / 256, 256, 0, stream>>>(
      (const float4*)partial, R, S, t, Rgt, Sgt, tgt, out);
}